// Round 1
// baseline (2183.913 us; speedup 1.0000x reference)
//
#include <hip/hip_runtime.h>

// ProteinGCN: 2x GCNConv(+relu) + FC head.
// N=100000 nodes, E=1600000 edges, dims 64 -> 128 -> 64 -> 1.
// Round 0: straightforward atomic-scatter implementation to get a correct
// baseline + profile. Expected bottleneck: fp32 atomics in scatter kernels.

constexpr int NN = 100000;
constexpr int NE = 1600000;
constexpr int D0 = 64;   // input dim
constexpr int D1 = 128;  // hidden 1
constexpr int D2 = 64;   // hidden 2

// ---------------- degree / dinv ----------------

__global__ __launch_bounds__(256) void k_init_deg(float* __restrict__ deg) {
    int i = blockIdx.x * 256 + threadIdx.x;
    if (i < NN) deg[i] = 1.0f;  // self-loop
}

__global__ __launch_bounds__(256) void k_count_deg(const int* __restrict__ dst,
                                                   float* __restrict__ deg) {
    int i = blockIdx.x * 256 + threadIdx.x;
    int stride = gridDim.x * 256;
    for (int e = i; e < NE; e += stride)
        unsafeAtomicAdd(&deg[dst[e]], 1.0f);
}

__global__ __launch_bounds__(256) void k_dinv(float* __restrict__ deg) {
    int i = blockIdx.x * 256 + threadIdx.x;
    if (i < NN) deg[i] = rsqrtf(deg[i]);
}

// ---------------- layer 1: y1 = (x @ W1) * dinv ; agg1 = y1 (self loop) ----

__global__ __launch_bounds__(256) void k_gemm1(const float* __restrict__ x,
                                               const float* __restrict__ W1,
                                               const float* __restrict__ dinv,
                                               float* __restrict__ y1,
                                               float* __restrict__ agg1) {
    int tid = threadIdx.x;
    int f = tid & (D1 - 1);           // 0..127
    int n = blockIdx.x * 2 + (tid >> 7);
    if (n >= NN) return;
    const float* xr = x + n * D0;
    float acc = 0.f;
#pragma unroll
    for (int k = 0; k < D0; ++k)
        acc = fmaf(xr[k], W1[k * D1 + f], acc);
    acc *= dinv[n];
    y1[n * D1 + f] = acc;
    agg1[n * D1 + f] = acc;
}

// one wave per edge, lane i handles features 2i, 2i+1 (float2 = 512B/wave)
__global__ __launch_bounds__(256) void k_scatter1(const int* __restrict__ src,
                                                  const int* __restrict__ dst,
                                                  const float* __restrict__ y1,
                                                  float* __restrict__ agg1) {
    int gid = blockIdx.x * 256 + threadIdx.x;
    int wave = gid >> 6;
    int lane = threadIdx.x & 63;
    int nw = (gridDim.x * 256) >> 6;
    for (int e = wave; e < NE; e += nw) {
        int s = src[e], d = dst[e];
        float2 v = *(const float2*)(y1 + s * D1 + lane * 2);
        unsafeAtomicAdd(&agg1[d * D1 + lane * 2 + 0], v.x);
        unsafeAtomicAdd(&agg1[d * D1 + lane * 2 + 1], v.y);
    }
}

// ---------------- layer 2: fused epilogue1 + GEMM2 ----------------
// h1[n,k] = relu(agg1[n,k]*dinv[n] + b1[k]);  y2[n,f] = (h1 @ W2)[n,f]*dinv[n]
__global__ __launch_bounds__(256) void k_gemm2(const float* __restrict__ agg1,
                                               const float* __restrict__ W2,
                                               const float* __restrict__ b1,
                                               const float* __restrict__ dinv,
                                               float* __restrict__ y2,
                                               float* __restrict__ agg2) {
    int tid = threadIdx.x;
    int f = tid & (D2 - 1);           // 0..63
    int n = blockIdx.x * 4 + (tid >> 6);
    if (n >= NN) return;
    float di = dinv[n];
    const float* ar = agg1 + n * D1;
    float acc = 0.f;
#pragma unroll 8
    for (int k = 0; k < D1; ++k) {
        float h = fmaxf(fmaf(ar[k], di, b1[k]), 0.f);
        acc = fmaf(h, W2[k * D2 + f], acc);
    }
    acc *= di;
    y2[n * D2 + f] = acc;
    agg2[n * D2 + f] = acc;
}

// one wave per edge, lane i handles feature i (256B/wave)
__global__ __launch_bounds__(256) void k_scatter2(const int* __restrict__ src,
                                                  const int* __restrict__ dst,
                                                  const float* __restrict__ y2,
                                                  float* __restrict__ agg2) {
    int gid = blockIdx.x * 256 + threadIdx.x;
    int wave = gid >> 6;
    int lane = threadIdx.x & 63;
    int nw = (gridDim.x * 256) >> 6;
    for (int e = wave; e < NE; e += nw) {
        int s = src[e], d = dst[e];
        float v = y2[s * D2 + lane];
        unsafeAtomicAdd(&agg2[d * D2 + lane], v);
    }
}

// ---------------- final: relu(agg2*dinv + b2) @ Wfc + bfc ----------------
__global__ __launch_bounds__(256) void k_final(const float* __restrict__ agg2,
                                               const float* __restrict__ dinv,
                                               const float* __restrict__ b2,
                                               const float* __restrict__ Wfc,
                                               const float* __restrict__ bfc,
                                               float* __restrict__ out) {
    int gid = blockIdx.x * 256 + threadIdx.x;
    int n = gid >> 6;
    int lane = threadIdx.x & 63;
    if (n >= NN) return;
    float v = agg2[n * D2 + lane];
    float h = fmaxf(fmaf(v, dinv[n], b2[lane]), 0.f);
    float p = h * Wfc[lane];
#pragma unroll
    for (int off = 32; off > 0; off >>= 1)
        p += __shfl_down(p, off, 64);
    if (lane == 0) out[n] = p + bfc[0];
}

extern "C" void kernel_launch(void* const* d_in, const int* in_sizes, int n_in,
                              void* d_out, int out_size, void* d_ws, size_t ws_size,
                              hipStream_t stream) {
    const float* x   = (const float*)d_in[0];
    const int*   ei  = (const int*)d_in[1];   // [2, E] int
    const float* W1  = (const float*)d_in[2];
    const float* b1  = (const float*)d_in[3];
    const float* W2  = (const float*)d_in[4];
    const float* b2  = (const float*)d_in[5];
    const float* Wfc = (const float*)d_in[6];
    const float* bfc = (const float*)d_in[7];
    float* out = (float*)d_out;

    const int* src = ei;
    const int* dst = ei + NE;

    char* ws = (char*)d_ws;
    // layout: deg/dinv [0, 400KB) ; y1 @1MB (51.2MB) ; agg1 after (51.2MB)
    // y2/agg2 alias the dead y1 region after scatter1 completes.
    float* deg  = (float*)(ws);
    float* y1   = (float*)(ws + (1u << 20));
    float* agg1 = (float*)(ws + (1u << 20) + (size_t)NN * D1 * 4);
    float* y2   = y1;                                     // reuse
    float* agg2 = (float*)(ws + (1u << 20) + (size_t)NN * D2 * 4);

    k_init_deg<<<(NN + 255) / 256, 256, 0, stream>>>(deg);
    k_count_deg<<<2048, 256, 0, stream>>>(dst, deg);
    k_dinv<<<(NN + 255) / 256, 256, 0, stream>>>(deg);

    k_gemm1<<<NN / 2, 256, 0, stream>>>(x, W1, deg, y1, agg1);
    k_scatter1<<<4096, 256, 0, stream>>>(src, dst, y1, agg1);

    k_gemm2<<<NN / 4, 256, 0, stream>>>(agg1, W2, b1, deg, y2, agg2);
    k_scatter2<<<4096, 256, 0, stream>>>(src, dst, y2, agg2);

    k_final<<<(NN * 64 + 255) / 256, 256, 0, stream>>>(agg2, deg, b2, Wfc, bfc, out);
}

// Round 2
// 851.513 us; speedup vs baseline: 2.5647x; 2.5647x over previous
//
#include <hip/hip_runtime.h>

// ProteinGCN: 2x GCNConv(+relu) + FC head. N=100k, E=1.6M, 64->128->64->1.
// Round 1: replace fp32 atomic scatters (1.95 ms, WRITE_SIZE 1.6 GB) with a
// per-call CSR build + gather-based aggregation (one wave per dst node,
// coalesced row reads, single streaming row write). Layer-2 gather fuses the
// FC head, deleting agg2 + k_final.

constexpr int NN = 100000;
constexpr int NE = 1600000;
constexpr int D0 = 64;   // input dim
constexpr int D1 = 128;  // hidden 1
constexpr int D2 = 64;   // hidden 2
constexpr int NB = (NN + 255) / 256;  // 391 scan blocks

// ---------------- CSR build ----------------

__global__ __launch_bounds__(256) void k_zero_cnt(int* __restrict__ cnt) {
    int i = blockIdx.x * 256 + threadIdx.x;
    if (i < NN) cnt[i] = 0;
}

__global__ __launch_bounds__(256) void k_hist(const int* __restrict__ dst,
                                              int* __restrict__ cnt) {
    int e = blockIdx.x * 256 + threadIdx.x;
    if (e < NE) atomicAdd(&cnt[dst[e]], 1);
}

// per-block exclusive scan of cnt -> rowptr, block totals -> bsum
__global__ __launch_bounds__(256) void k_scan_block(const int* __restrict__ cnt,
                                                    int* __restrict__ rowptr,
                                                    int* __restrict__ bsum) {
    __shared__ int s[256];
    int tid = threadIdx.x;
    int i = blockIdx.x * 256 + tid;
    int v = (i < NN) ? cnt[i] : 0;
    s[tid] = v;
    __syncthreads();
#pragma unroll
    for (int off = 1; off < 256; off <<= 1) {
        int t = (tid >= off) ? s[tid - off] : 0;
        __syncthreads();
        s[tid] += t;
        __syncthreads();
    }
    if (i < NN) rowptr[i] = s[tid] - v;  // exclusive
    if (tid == 255) bsum[blockIdx.x] = s[255];
}

// single block: exclusive scan of the 391 block sums in-place
__global__ __launch_bounds__(512) void k_scan_bsum(int* __restrict__ bsum) {
    __shared__ int s[512];
    int tid = threadIdx.x;
    int v = (tid < NB) ? bsum[tid] : 0;
    s[tid] = v;
    __syncthreads();
#pragma unroll
    for (int off = 1; off < 512; off <<= 1) {
        int t = (tid >= off) ? s[tid - off] : 0;
        __syncthreads();
        s[tid] += t;
        __syncthreads();
    }
    if (tid < NB) bsum[tid] = s[tid] - v;  // exclusive
}

__global__ __launch_bounds__(256) void k_scan_add(int* __restrict__ rowptr,
                                                  const int* __restrict__ bsum) {
    int i = blockIdx.x * 256 + threadIdx.x;
    if (i < NN) rowptr[i] += bsum[i >> 8];
    if (i == 0) rowptr[NN] = NE;
}

// dinv[i] = rsqrt(deg_in+1); cursor[i] = rowptr[i]  (cursor aliases cnt: read
// cnt first, then overwrite)
__global__ __launch_bounds__(256) void k_dinv_cursor(const int* __restrict__ rowptr,
                                                     int* __restrict__ cnt_cursor,
                                                     float* __restrict__ dinv) {
    int i = blockIdx.x * 256 + threadIdx.x;
    if (i >= NN) return;
    int c = cnt_cursor[i];
    dinv[i] = rsqrtf((float)(c + 1));
    cnt_cursor[i] = rowptr[i];
}

__global__ __launch_bounds__(256) void k_fill(const int* __restrict__ src,
                                              const int* __restrict__ dst,
                                              int* __restrict__ cursor,
                                              int* __restrict__ col) {
    int e = blockIdx.x * 256 + threadIdx.x;
    if (e < NE) {
        int pos = atomicAdd(&cursor[dst[e]], 1);
        col[pos] = src[e];
    }
}

// ---------------- layer 1: y1 = (x @ W1) * dinv ----------------

__global__ __launch_bounds__(256) void k_gemm1(const float* __restrict__ x,
                                               const float* __restrict__ W1,
                                               const float* __restrict__ dinv,
                                               float* __restrict__ y1) {
    int tid = threadIdx.x;
    int f = tid & (D1 - 1);           // 0..127
    int n = blockIdx.x * 2 + (tid >> 7);
    if (n >= NN) return;
    const float* xr = x + (size_t)n * D0;
    float acc = 0.f;
#pragma unroll
    for (int k = 0; k < D0; ++k)
        acc = fmaf(xr[k], W1[k * D1 + f], acc);
    y1[(size_t)n * D1 + f] = acc * dinv[n];
}

// one wave per dst node: agg1[n] = y1[n] + sum_{s in in(n)} y1[s]
__global__ __launch_bounds__(256) void k_gather1(const int* __restrict__ rowptr,
                                                 const int* __restrict__ col,
                                                 const float* __restrict__ y1,
                                                 float* __restrict__ agg1) {
    int wave = (blockIdx.x * 256 + threadIdx.x) >> 6;
    int lane = threadIdx.x & 63;
    if (wave >= NN) return;
    int r0 = rowptr[wave], r1 = rowptr[wave + 1];
    float2 acc = *(const float2*)(y1 + (size_t)wave * D1 + lane * 2);
    int e = r0;
    for (; e + 1 < r1; e += 2) {
        int s0 = col[e], s1 = col[e + 1];
        float2 v0 = *(const float2*)(y1 + (size_t)s0 * D1 + lane * 2);
        float2 v1 = *(const float2*)(y1 + (size_t)s1 * D1 + lane * 2);
        acc.x += v0.x; acc.y += v0.y;
        acc.x += v1.x; acc.y += v1.y;
    }
    if (e < r1) {
        int s0 = col[e];
        float2 v0 = *(const float2*)(y1 + (size_t)s0 * D1 + lane * 2);
        acc.x += v0.x; acc.y += v0.y;
    }
    *(float2*)(agg1 + (size_t)wave * D1 + lane * 2) = acc;
}

// ---------------- layer 2: fused epilogue1 + GEMM2 ----------------
// h1[n,k] = relu(agg1[n,k]*dinv[n] + b1[k]);  y2[n,f] = (h1 @ W2)[n,f]*dinv[n]
__global__ __launch_bounds__(256) void k_gemm2(const float* __restrict__ agg1,
                                               const float* __restrict__ W2,
                                               const float* __restrict__ b1,
                                               const float* __restrict__ dinv,
                                               float* __restrict__ y2) {
    int tid = threadIdx.x;
    int f = tid & (D2 - 1);           // 0..63
    int n = blockIdx.x * 4 + (tid >> 6);
    if (n >= NN) return;
    float di = dinv[n];
    const float* ar = agg1 + (size_t)n * D1;
    float acc = 0.f;
#pragma unroll 8
    for (int k = 0; k < D1; ++k) {
        float h = fmaxf(fmaf(ar[k], di, b1[k]), 0.f);
        acc = fmaf(h, W2[k * D2 + f], acc);
    }
    y2[(size_t)n * D2 + f] = acc * di;
}

// ---------------- layer-2 gather fused with FC head ----------------
// agg2[n] = y2[n] + sum y2[s]; out[n] = relu(agg2*dinv+b2) . Wfc + bfc
__global__ __launch_bounds__(256) void k_gather2_final(const int* __restrict__ rowptr,
                                                       const int* __restrict__ col,
                                                       const float* __restrict__ y2,
                                                       const float* __restrict__ dinv,
                                                       const float* __restrict__ b2,
                                                       const float* __restrict__ Wfc,
                                                       const float* __restrict__ bfc,
                                                       float* __restrict__ out) {
    int wave = (blockIdx.x * 256 + threadIdx.x) >> 6;
    int lane = threadIdx.x & 63;
    if (wave >= NN) return;
    int r0 = rowptr[wave], r1 = rowptr[wave + 1];
    float acc = y2[(size_t)wave * D2 + lane];
    int e = r0;
    for (; e + 1 < r1; e += 2) {
        int s0 = col[e], s1 = col[e + 1];
        float v0 = y2[(size_t)s0 * D2 + lane];
        float v1 = y2[(size_t)s1 * D2 + lane];
        acc += v0 + v1;
    }
    if (e < r1) acc += y2[(size_t)col[e] * D2 + lane];
    float h = fmaxf(fmaf(acc, dinv[wave], b2[lane]), 0.f);
    float p = h * Wfc[lane];
#pragma unroll
    for (int off = 32; off > 0; off >>= 1)
        p += __shfl_down(p, off, 64);
    if (lane == 0) out[wave] = p + bfc[0];
}

extern "C" void kernel_launch(void* const* d_in, const int* in_sizes, int n_in,
                              void* d_out, int out_size, void* d_ws, size_t ws_size,
                              hipStream_t stream) {
    const float* x   = (const float*)d_in[0];
    const int*   ei  = (const int*)d_in[1];   // [2, E] int
    const float* W1  = (const float*)d_in[2];
    const float* b1  = (const float*)d_in[3];
    const float* W2  = (const float*)d_in[4];
    const float* b2  = (const float*)d_in[5];
    const float* Wfc = (const float*)d_in[6];
    const float* bfc = (const float*)d_in[7];
    float* out = (float*)d_out;

    const int* src = ei;
    const int* dst = ei + NE;

    char* ws = (char*)d_ws;
    size_t o = 0;
    auto alloc = [&](size_t bytes) { char* p = ws + o; o += (bytes + 255) & ~size_t(255); return p; };
    int*   cnt    = (int*)alloc(NN * 4);        // later reused as fill cursor
    int*   rowptr = (int*)alloc((NN + 1) * 4);
    int*   bsum   = (int*)alloc(512 * 4);
    float* dinv   = (float*)alloc(NN * 4);
    int*   col    = (int*)alloc((size_t)NE * 4);
    float* y1     = (float*)alloc((size_t)NN * D1 * 4);  // y2 aliases y1
    float* agg1   = (float*)alloc((size_t)NN * D1 * 4);
    float* y2     = y1;

    const int NBn = (NN + 255) / 256;
    const int NBe = (NE + 255) / 256;

    k_zero_cnt   <<<NBn, 256, 0, stream>>>(cnt);
    k_hist       <<<NBe, 256, 0, stream>>>(dst, cnt);
    k_scan_block <<<NBn, 256, 0, stream>>>(cnt, rowptr, bsum);
    k_scan_bsum  <<<1, 512, 0, stream>>>(bsum);
    k_scan_add   <<<NBn, 256, 0, stream>>>(rowptr, bsum);
    k_dinv_cursor<<<NBn, 256, 0, stream>>>(rowptr, cnt, dinv);
    k_fill       <<<NBe, 256, 0, stream>>>(src, dst, cnt, col);

    k_gemm1      <<<NN / 2, 256, 0, stream>>>(x, W1, dinv, y1);
    k_gather1    <<<(NN * 64 + 255) / 256, 256, 0, stream>>>(rowptr, col, y1, agg1);
    k_gemm2      <<<NN / 4, 256, 0, stream>>>(agg1, W2, b1, dinv, y2);
    k_gather2_final<<<(NN * 64 + 255) / 256, 256, 0, stream>>>(rowptr, col, y2, dinv,
                                                               b2, Wfc, bfc, out);
}

// Round 3
// 541.788 us; speedup vs baseline: 4.0309x; 1.5717x over previous
//
#include <hip/hip_runtime.h>

// ProteinGCN: 2x GCNConv(+relu) + FC head. N=100k, E=1.6M, 64->128->64->1.
// Round 2: register-blocked fp32 GEMMs (4 nodes x 4 feats per thread, LDS-staged
// node rows, float4 weight loads from L1) and relu-epilogue fused into gather1
// (computed once per feature, not 64x per node). Gather edge loops 4-wide.

constexpr int NN = 100000;
constexpr int NE = 1600000;
constexpr int D0 = 64;   // input dim
constexpr int D1 = 128;  // hidden 1
constexpr int D2 = 64;   // hidden 2
constexpr int NB = (NN + 255) / 256;  // 391 scan blocks
constexpr int H2STRIDE = 132;         // LDS row stride for gemm2 (16B aligned, 2-way banks)

// ---------------- CSR build ----------------

__global__ __launch_bounds__(256) void k_zero_cnt(int* __restrict__ cnt) {
    int i = blockIdx.x * 256 + threadIdx.x;
    if (i < NN) cnt[i] = 0;
}

__global__ __launch_bounds__(256) void k_hist(const int* __restrict__ dst,
                                              int* __restrict__ cnt) {
    int e = blockIdx.x * 256 + threadIdx.x;
    if (e < NE) atomicAdd(&cnt[dst[e]], 1);
}

__global__ __launch_bounds__(256) void k_scan_block(const int* __restrict__ cnt,
                                                    int* __restrict__ rowptr,
                                                    int* __restrict__ bsum) {
    __shared__ int s[256];
    int tid = threadIdx.x;
    int i = blockIdx.x * 256 + tid;
    int v = (i < NN) ? cnt[i] : 0;
    s[tid] = v;
    __syncthreads();
#pragma unroll
    for (int off = 1; off < 256; off <<= 1) {
        int t = (tid >= off) ? s[tid - off] : 0;
        __syncthreads();
        s[tid] += t;
        __syncthreads();
    }
    if (i < NN) rowptr[i] = s[tid] - v;  // exclusive
    if (tid == 255) bsum[blockIdx.x] = s[255];
}

__global__ __launch_bounds__(512) void k_scan_bsum(int* __restrict__ bsum) {
    __shared__ int s[512];
    int tid = threadIdx.x;
    int v = (tid < NB) ? bsum[tid] : 0;
    s[tid] = v;
    __syncthreads();
#pragma unroll
    for (int off = 1; off < 512; off <<= 1) {
        int t = (tid >= off) ? s[tid - off] : 0;
        __syncthreads();
        s[tid] += t;
        __syncthreads();
    }
    if (tid < NB) bsum[tid] = s[tid] - v;  // exclusive
}

__global__ __launch_bounds__(256) void k_scan_add(int* __restrict__ rowptr,
                                                  const int* __restrict__ bsum) {
    int i = blockIdx.x * 256 + threadIdx.x;
    if (i < NN) rowptr[i] += bsum[i >> 8];
    if (i == 0) rowptr[NN] = NE;
}

__global__ __launch_bounds__(256) void k_dinv_cursor(const int* __restrict__ rowptr,
                                                     int* __restrict__ cnt_cursor,
                                                     float* __restrict__ dinv) {
    int i = blockIdx.x * 256 + threadIdx.x;
    if (i >= NN) return;
    int c = cnt_cursor[i];
    dinv[i] = rsqrtf((float)(c + 1));
    cnt_cursor[i] = rowptr[i];
}

__global__ __launch_bounds__(256) void k_fill(const int* __restrict__ src,
                                              const int* __restrict__ dst,
                                              int* __restrict__ cursor,
                                              int* __restrict__ col) {
    int e = blockIdx.x * 256 + threadIdx.x;
    if (e < NE) {
        int pos = atomicAdd(&cursor[dst[e]], 1);
        col[pos] = src[e];
    }
}

// ---------------- helpers ----------------

__device__ __forceinline__ void fma4(float4& acc, float s, const float4& w) {
    acc.x = fmaf(s, w.x, acc.x);
    acc.y = fmaf(s, w.y, acc.y);
    acc.z = fmaf(s, w.z, acc.z);
    acc.w = fmaf(s, w.w, acc.w);
}

__device__ __forceinline__ float4 scale4(const float4& a, float s) {
    return float4{a.x * s, a.y * s, a.z * s, a.w * s};
}

// ---------------- layer 1 GEMM: y1 = (x @ W1) * dinv ----------------
// block = 256 threads = 8 node-groups(of 4) x 32 f-quads; 32 nodes/block.
// NN = 3125 * 32 exactly.
__global__ __launch_bounds__(256) void k_gemm1(const float* __restrict__ x,
                                               const float* __restrict__ W1,
                                               const float* __restrict__ dinv,
                                               float* __restrict__ y1) {
    __shared__ float xs[32 * D0];  // 8 KB
    int tid = threadIdx.x;
    const float4* xb = (const float4*)(x + (size_t)blockIdx.x * 32 * D0);
    float4* xs4 = (float4*)xs;
    xs4[tid] = xb[tid];
    xs4[tid + 256] = xb[tid + 256];
    __syncthreads();

    int fq = tid & 31;   // f = fq*4
    int ng = tid >> 5;   // node group 0..7
    const float4* W14 = (const float4*)W1;  // [64][32] float4
    const float* xr = xs + ng * 4 * D0;
    float4 acc0{0, 0, 0, 0}, acc1{0, 0, 0, 0}, acc2{0, 0, 0, 0}, acc3{0, 0, 0, 0};

#pragma unroll 2
    for (int k = 0; k < D0; k += 4) {
        float4 a0 = *(const float4*)(xr + k);
        float4 a1 = *(const float4*)(xr + D0 + k);
        float4 a2 = *(const float4*)(xr + 2 * D0 + k);
        float4 a3 = *(const float4*)(xr + 3 * D0 + k);
        float4 w0 = W14[(k + 0) * 32 + fq];
        float4 w1 = W14[(k + 1) * 32 + fq];
        float4 w2 = W14[(k + 2) * 32 + fq];
        float4 w3 = W14[(k + 3) * 32 + fq];
        fma4(acc0, a0.x, w0); fma4(acc0, a0.y, w1); fma4(acc0, a0.z, w2); fma4(acc0, a0.w, w3);
        fma4(acc1, a1.x, w0); fma4(acc1, a1.y, w1); fma4(acc1, a1.z, w2); fma4(acc1, a1.w, w3);
        fma4(acc2, a2.x, w0); fma4(acc2, a2.y, w1); fma4(acc2, a2.z, w2); fma4(acc2, a2.w, w3);
        fma4(acc3, a3.x, w0); fma4(acc3, a3.y, w1); fma4(acc3, a3.z, w2); fma4(acc3, a3.w, w3);
    }

    int n0 = blockIdx.x * 32 + ng * 4;
    float4* y14 = (float4*)y1;  // [N][32] float4
    y14[(size_t)(n0 + 0) * 32 + fq] = scale4(acc0, dinv[n0 + 0]);
    y14[(size_t)(n0 + 1) * 32 + fq] = scale4(acc1, dinv[n0 + 1]);
    y14[(size_t)(n0 + 2) * 32 + fq] = scale4(acc2, dinv[n0 + 2]);
    y14[(size_t)(n0 + 3) * 32 + fq] = scale4(acc3, dinv[n0 + 3]);
}

// ---------------- gather1 + fused epilogue -> h1 ----------------
// h1[n,f] = relu((y1[n,f] + sum_{s in in(n)} y1[s,f]) * dinv[n] + b1[f])
__global__ __launch_bounds__(256) void k_gather1(const int* __restrict__ rowptr,
                                                 const int* __restrict__ col,
                                                 const float* __restrict__ y1,
                                                 const float* __restrict__ dinv,
                                                 const float* __restrict__ b1,
                                                 float* __restrict__ h1) {
    int wave = (blockIdx.x * 256 + threadIdx.x) >> 6;
    int lane = threadIdx.x & 63;
    if (wave >= NN) return;
    int r0 = rowptr[wave], r1 = rowptr[wave + 1];
    float2 acc = *(const float2*)(y1 + (size_t)wave * D1 + lane * 2);
    int e = r0;
    for (; e + 3 < r1; e += 4) {
        int s0 = col[e], s1 = col[e + 1], s2 = col[e + 2], s3 = col[e + 3];
        float2 v0 = *(const float2*)(y1 + (size_t)s0 * D1 + lane * 2);
        float2 v1 = *(const float2*)(y1 + (size_t)s1 * D1 + lane * 2);
        float2 v2 = *(const float2*)(y1 + (size_t)s2 * D1 + lane * 2);
        float2 v3 = *(const float2*)(y1 + (size_t)s3 * D1 + lane * 2);
        acc.x += (v0.x + v1.x) + (v2.x + v3.x);
        acc.y += (v0.y + v1.y) + (v2.y + v3.y);
    }
    for (; e < r1; ++e) {
        int s0 = col[e];
        float2 v0 = *(const float2*)(y1 + (size_t)s0 * D1 + lane * 2);
        acc.x += v0.x; acc.y += v0.y;
    }
    float di = dinv[wave];
    float2 b = *(const float2*)(b1 + lane * 2);
    float2 h;
    h.x = fmaxf(fmaf(acc.x, di, b.x), 0.f);
    h.y = fmaxf(fmaf(acc.y, di, b.y), 0.f);
    *(float2*)(h1 + (size_t)wave * D1 + lane * 2) = h;
}

// ---------------- layer 2 GEMM: y2 = (h1 @ W2) * dinv ----------------
// block = 256 = 16 node-groups(of 4) x 16 f-quads; 64 nodes/block.
__global__ __launch_bounds__(256) void k_gemm2(const float* __restrict__ h1,
                                               const float* __restrict__ W2,
                                               const float* __restrict__ dinv,
                                               float* __restrict__ y2) {
    __shared__ float hs[64 * H2STRIDE];  // ~33 KB
    int tid = threadIdx.x;
    int n_base = blockIdx.x * 64;
    // stage 64 rows (128 floats each) with padded stride
    {
        int r = tid >> 5;        // 0..7
        int c4 = tid & 31;       // float4 col 0..31
#pragma unroll
        for (int i = 0; i < 8; ++i) {
            int row = r + i * 8;
            int n = n_base + row;
            float4 v{0, 0, 0, 0};
            if (n < NN) v = *(const float4*)(h1 + (size_t)n * D1 + c4 * 4);
            *(float4*)(hs + row * H2STRIDE + c4 * 4) = v;
        }
    }
    __syncthreads();

    int fq = tid & 15;   // f = fq*4, 0..63
    int ng = tid >> 4;   // 0..15, 4 nodes each
    const float* hr = hs + ng * 4 * H2STRIDE;
    const float4* W24 = (const float4*)W2;  // [128][16] float4
    float4 acc0{0, 0, 0, 0}, acc1{0, 0, 0, 0}, acc2{0, 0, 0, 0}, acc3{0, 0, 0, 0};

#pragma unroll 2
    for (int k = 0; k < D1; k += 4) {
        float4 a0 = *(const float4*)(hr + k);
        float4 a1 = *(const float4*)(hr + H2STRIDE + k);
        float4 a2 = *(const float4*)(hr + 2 * H2STRIDE + k);
        float4 a3 = *(const float4*)(hr + 3 * H2STRIDE + k);
        float4 w0 = W24[(k + 0) * 16 + fq];
        float4 w1 = W24[(k + 1) * 16 + fq];
        float4 w2 = W24[(k + 2) * 16 + fq];
        float4 w3 = W24[(k + 3) * 16 + fq];
        fma4(acc0, a0.x, w0); fma4(acc0, a0.y, w1); fma4(acc0, a0.z, w2); fma4(acc0, a0.w, w3);
        fma4(acc1, a1.x, w0); fma4(acc1, a1.y, w1); fma4(acc1, a1.z, w2); fma4(acc1, a1.w, w3);
        fma4(acc2, a2.x, w0); fma4(acc2, a2.y, w1); fma4(acc2, a2.z, w2); fma4(acc2, a2.w, w3);
        fma4(acc3, a3.x, w0); fma4(acc3, a3.y, w1); fma4(acc3, a3.z, w2); fma4(acc3, a3.w, w3);
    }

    int n0 = n_base + ng * 4;
    float4* y24 = (float4*)y2;  // [N][16] float4
    if (n0 + 0 < NN) y24[(size_t)(n0 + 0) * 16 + fq] = scale4(acc0, dinv[n0 + 0]);
    if (n0 + 1 < NN) y24[(size_t)(n0 + 1) * 16 + fq] = scale4(acc1, dinv[n0 + 1]);
    if (n0 + 2 < NN) y24[(size_t)(n0 + 2) * 16 + fq] = scale4(acc2, dinv[n0 + 2]);
    if (n0 + 3 < NN) y24[(size_t)(n0 + 3) * 16 + fq] = scale4(acc3, dinv[n0 + 3]);
}

// ---------------- layer-2 gather fused with FC head ----------------
__global__ __launch_bounds__(256) void k_gather2_final(const int* __restrict__ rowptr,
                                                       const int* __restrict__ col,
                                                       const float* __restrict__ y2,
                                                       const float* __restrict__ dinv,
                                                       const float* __restrict__ b2,
                                                       const float* __restrict__ Wfc,
                                                       const float* __restrict__ bfc,
                                                       float* __restrict__ out) {
    int wave = (blockIdx.x * 256 + threadIdx.x) >> 6;
    int lane = threadIdx.x & 63;
    if (wave >= NN) return;
    int r0 = rowptr[wave], r1 = rowptr[wave + 1];
    float acc = y2[(size_t)wave * D2 + lane];
    int e = r0;
    for (; e + 3 < r1; e += 4) {
        int s0 = col[e], s1 = col[e + 1], s2 = col[e + 2], s3 = col[e + 3];
        float v0 = y2[(size_t)s0 * D2 + lane];
        float v1 = y2[(size_t)s1 * D2 + lane];
        float v2 = y2[(size_t)s2 * D2 + lane];
        float v3 = y2[(size_t)s3 * D2 + lane];
        acc += (v0 + v1) + (v2 + v3);
    }
    for (; e < r1; ++e) acc += y2[(size_t)col[e] * D2 + lane];
    float h = fmaxf(fmaf(acc, dinv[wave], b2[lane]), 0.f);
    float p = h * Wfc[lane];
#pragma unroll
    for (int off = 32; off > 0; off >>= 1)
        p += __shfl_down(p, off, 64);
    if (lane == 0) out[wave] = p + bfc[0];
}

extern "C" void kernel_launch(void* const* d_in, const int* in_sizes, int n_in,
                              void* d_out, int out_size, void* d_ws, size_t ws_size,
                              hipStream_t stream) {
    const float* x   = (const float*)d_in[0];
    const int*   ei  = (const int*)d_in[1];   // [2, E] int
    const float* W1  = (const float*)d_in[2];
    const float* b1  = (const float*)d_in[3];
    const float* W2  = (const float*)d_in[4];
    const float* b2  = (const float*)d_in[5];
    const float* Wfc = (const float*)d_in[6];
    const float* bfc = (const float*)d_in[7];
    float* out = (float*)d_out;

    const int* src = ei;
    const int* dst = ei + NE;

    char* ws = (char*)d_ws;
    size_t o = 0;
    auto alloc = [&](size_t bytes) { char* p = ws + o; o += (bytes + 255) & ~size_t(255); return p; };
    int*   cnt    = (int*)alloc(NN * 4);        // later reused as fill cursor
    int*   rowptr = (int*)alloc((NN + 1) * 4);
    int*   bsum   = (int*)alloc(512 * 4);
    float* dinv   = (float*)alloc(NN * 4);
    int*   col    = (int*)alloc((size_t)NE * 4);
    float* y1     = (float*)alloc((size_t)NN * D1 * 4);  // y2 aliases y1 (dead after gather1)
    float* h1     = (float*)alloc((size_t)NN * D1 * 4);
    float* y2     = y1;

    const int NBn = (NN + 255) / 256;
    const int NBe = (NE + 255) / 256;

    k_zero_cnt   <<<NBn, 256, 0, stream>>>(cnt);
    k_hist       <<<NBe, 256, 0, stream>>>(dst, cnt);
    k_scan_block <<<NBn, 256, 0, stream>>>(cnt, rowptr, bsum);
    k_scan_bsum  <<<1, 512, 0, stream>>>(bsum);
    k_scan_add   <<<NBn, 256, 0, stream>>>(rowptr, bsum);
    k_dinv_cursor<<<NBn, 256, 0, stream>>>(rowptr, cnt, dinv);
    k_fill       <<<NBe, 256, 0, stream>>>(src, dst, cnt, col);

    k_gemm1      <<<NN / 32, 256, 0, stream>>>(x, W1, dinv, y1);
    k_gather1    <<<(NN * 64 + 255) / 256, 256, 0, stream>>>(rowptr, col, y1, dinv, b1, h1);
    k_gemm2      <<<(NN + 63) / 64, 256, 0, stream>>>(h1, W2, dinv, y2);
    k_gather2_final<<<(NN * 64 + 255) / 256, 256, 0, stream>>>(rowptr, col, y2, dinv,
                                                               b2, Wfc, bfc, out);
}

// Round 4
// 450.957 us; speedup vs baseline: 4.8428x; 1.2014x over previous
//
#include <hip/hip_runtime.h>

// ProteinGCN: 2x GCNConv(+relu) + FC head. N=100k, E=1.6M, 64->128->64->1.
// Round 3: k_fill (131 us, WRITE_SIZE 105 MB for a 6.4 MB col array -- every
// random 4B write dirtied a 64B line) replaced by a two-phase fill:
//   k_part : tile-local bucket partition (bucket = dst>>8, 256 nodes) with
//            per-tile chunk reservation -> packed writes merge in the block's
//            own XCD L2 (~6.4 MB writes).
//   k_fill2: one block per bucket, LDS per-node cursors, col writes confined
//            to the bucket's contiguous ~16 KB slice -> merged in L2.
// packed aliases h1 (dead until gemm1). Row order nondeterministic (fp-add
// reorder tolerated: absmax 4.9e-4 vs 3.75e-3 threshold).

constexpr int NN = 100000;
constexpr int NE = 1600000;
constexpr int D0 = 64;   // input dim
constexpr int D1 = 128;  // hidden 1
constexpr int D2 = 64;   // hidden 2
constexpr int NB = (NN + 255) / 256;  // 391 scan blocks == 391 buckets
constexpr int H2STRIDE = 132;         // LDS row stride for gemm2
constexpr int TILE = 8192;            // edges per k_part block

// ---------------- CSR build ----------------

__global__ __launch_bounds__(256) void k_zero_cnt(int* __restrict__ cnt) {
    int i = blockIdx.x * 256 + threadIdx.x;
    if (i < NN) cnt[i] = 0;
}

__global__ __launch_bounds__(256) void k_hist(const int* __restrict__ dst,
                                              int* __restrict__ cnt) {
    int e = blockIdx.x * 256 + threadIdx.x;
    if (e < NE) atomicAdd(&cnt[dst[e]], 1);
}

__global__ __launch_bounds__(256) void k_scan_block(const int* __restrict__ cnt,
                                                    int* __restrict__ rowptr,
                                                    int* __restrict__ bsum) {
    __shared__ int s[256];
    int tid = threadIdx.x;
    int i = blockIdx.x * 256 + tid;
    int v = (i < NN) ? cnt[i] : 0;
    s[tid] = v;
    __syncthreads();
#pragma unroll
    for (int off = 1; off < 256; off <<= 1) {
        int t = (tid >= off) ? s[tid - off] : 0;
        __syncthreads();
        s[tid] += t;
        __syncthreads();
    }
    if (i < NN) rowptr[i] = s[tid] - v;  // exclusive
    if (tid == 255) bsum[blockIdx.x] = s[255];
}

// scan 512 block sums; also seed gcur (phase-1 reservation cursors)
__global__ __launch_bounds__(512) void k_scan_bsum(int* __restrict__ bsum,
                                                   int* __restrict__ gcur) {
    __shared__ int s[512];
    int tid = threadIdx.x;
    int v = (tid < NB) ? bsum[tid] : 0;
    s[tid] = v;
    __syncthreads();
#pragma unroll
    for (int off = 1; off < 512; off <<= 1) {
        int t = (tid >= off) ? s[tid - off] : 0;
        __syncthreads();
        s[tid] += t;
        __syncthreads();
    }
    int ex = s[tid] - v;  // exclusive scan
    if (tid <= NB) bsum[tid] = ex;   // bsum[NB] == NE
    if (tid < NB) gcur[tid] = ex;
}

__global__ __launch_bounds__(256) void k_scan_add(int* __restrict__ rowptr,
                                                  const int* __restrict__ bsum) {
    int i = blockIdx.x * 256 + threadIdx.x;
    if (i < NN) rowptr[i] += bsum[i >> 8];
    if (i == 0) rowptr[NN] = NE;
}

__global__ __launch_bounds__(256) void k_dinv(const int* __restrict__ cnt,
                                              float* __restrict__ dinv) {
    int i = blockIdx.x * 256 + threadIdx.x;
    if (i < NN) dinv[i] = rsqrtf((float)(cnt[i] + 1));
}

// ---- phase 1: partition edges into 391 dst-buckets, packed (dl<<24)|src ----
__global__ __launch_bounds__(256) void k_part(const int* __restrict__ src,
                                              const int* __restrict__ dst,
                                              int* __restrict__ gcur,
                                              unsigned* __restrict__ packed) {
    __shared__ int cnt_s[NB];
    __shared__ int gbase_s[NB];
    __shared__ int cur_s[NB];
    int tid = threadIdx.x;
    int e0 = blockIdx.x * TILE;
    int ecnt = NE - e0 < TILE ? NE - e0 : TILE;
    for (int i = tid; i < NB; i += 256) cnt_s[i] = 0;
    __syncthreads();
    for (int i = tid; i < ecnt; i += 256)
        atomicAdd(&cnt_s[dst[e0 + i] >> 8], 1);
    __syncthreads();
    for (int i = tid; i < NB; i += 256) {
        int c = cnt_s[i];
        gbase_s[i] = c ? atomicAdd(&gcur[i], c) : 0;
        cur_s[i] = 0;
    }
    __syncthreads();
    for (int i = tid; i < ecnt; i += 256) {
        int d = dst[e0 + i];
        int s = src[e0 + i];
        int b = d >> 8;
        int slot = atomicAdd(&cur_s[b], 1);
        packed[gbase_s[b] + slot] = ((unsigned)(d & 255) << 24) | (unsigned)s;
    }
}

// ---- phase 2: one block per bucket, LDS node cursors, local col writes ----
__global__ __launch_bounds__(256) void k_fill2(const int* __restrict__ bsum,
                                               const int* __restrict__ rowptr,
                                               const unsigned* __restrict__ packed,
                                               int* __restrict__ col) {
    __shared__ int cur[256];
    int b = blockIdx.x;
    int n = (b << 8) + threadIdx.x;
    cur[threadIdx.x] = rowptr[n <= NN ? n : NN];
    __syncthreads();
    int e1 = bsum[b + 1];
    for (int e = bsum[b] + threadIdx.x; e < e1; e += 256) {
        unsigned p = packed[e];
        int pos = atomicAdd(&cur[p >> 24], 1);
        col[pos] = (int)(p & 0xFFFFFFu);
    }
}

// ---------------- helpers ----------------

__device__ __forceinline__ void fma4(float4& acc, float s, const float4& w) {
    acc.x = fmaf(s, w.x, acc.x);
    acc.y = fmaf(s, w.y, acc.y);
    acc.z = fmaf(s, w.z, acc.z);
    acc.w = fmaf(s, w.w, acc.w);
}

__device__ __forceinline__ float4 scale4(const float4& a, float s) {
    return float4{a.x * s, a.y * s, a.z * s, a.w * s};
}

// ---------------- layer 1 GEMM: y1 = (x @ W1) * dinv ----------------
__global__ __launch_bounds__(256) void k_gemm1(const float* __restrict__ x,
                                               const float* __restrict__ W1,
                                               const float* __restrict__ dinv,
                                               float* __restrict__ y1) {
    __shared__ float xs[32 * D0];  // 8 KB
    int tid = threadIdx.x;
    const float4* xb = (const float4*)(x + (size_t)blockIdx.x * 32 * D0);
    float4* xs4 = (float4*)xs;
    xs4[tid] = xb[tid];
    xs4[tid + 256] = xb[tid + 256];
    __syncthreads();

    int fq = tid & 31;   // f = fq*4
    int ng = tid >> 5;   // node group 0..7
    const float4* W14 = (const float4*)W1;  // [64][32] float4
    const float* xr = xs + ng * 4 * D0;
    float4 acc0{0, 0, 0, 0}, acc1{0, 0, 0, 0}, acc2{0, 0, 0, 0}, acc3{0, 0, 0, 0};

#pragma unroll 2
    for (int k = 0; k < D0; k += 4) {
        float4 a0 = *(const float4*)(xr + k);
        float4 a1 = *(const float4*)(xr + D0 + k);
        float4 a2 = *(const float4*)(xr + 2 * D0 + k);
        float4 a3 = *(const float4*)(xr + 3 * D0 + k);
        float4 w0 = W14[(k + 0) * 32 + fq];
        float4 w1 = W14[(k + 1) * 32 + fq];
        float4 w2 = W14[(k + 2) * 32 + fq];
        float4 w3 = W14[(k + 3) * 32 + fq];
        fma4(acc0, a0.x, w0); fma4(acc0, a0.y, w1); fma4(acc0, a0.z, w2); fma4(acc0, a0.w, w3);
        fma4(acc1, a1.x, w0); fma4(acc1, a1.y, w1); fma4(acc1, a1.z, w2); fma4(acc1, a1.w, w3);
        fma4(acc2, a2.x, w0); fma4(acc2, a2.y, w1); fma4(acc2, a2.z, w2); fma4(acc2, a2.w, w3);
        fma4(acc3, a3.x, w0); fma4(acc3, a3.y, w1); fma4(acc3, a3.z, w2); fma4(acc3, a3.w, w3);
    }

    int n0 = blockIdx.x * 32 + ng * 4;
    float4* y14 = (float4*)y1;  // [N][32] float4
    y14[(size_t)(n0 + 0) * 32 + fq] = scale4(acc0, dinv[n0 + 0]);
    y14[(size_t)(n0 + 1) * 32 + fq] = scale4(acc1, dinv[n0 + 1]);
    y14[(size_t)(n0 + 2) * 32 + fq] = scale4(acc2, dinv[n0 + 2]);
    y14[(size_t)(n0 + 3) * 32 + fq] = scale4(acc3, dinv[n0 + 3]);
}

// ---------------- gather1 + fused epilogue -> h1 ----------------
__global__ __launch_bounds__(256) void k_gather1(const int* __restrict__ rowptr,
                                                 const int* __restrict__ col,
                                                 const float* __restrict__ y1,
                                                 const float* __restrict__ dinv,
                                                 const float* __restrict__ b1,
                                                 float* __restrict__ h1) {
    int wave = (blockIdx.x * 256 + threadIdx.x) >> 6;
    int lane = threadIdx.x & 63;
    if (wave >= NN) return;
    int r0 = rowptr[wave], r1 = rowptr[wave + 1];
    float2 acc = *(const float2*)(y1 + (size_t)wave * D1 + lane * 2);
    int e = r0;
    for (; e + 3 < r1; e += 4) {
        int s0 = col[e], s1 = col[e + 1], s2 = col[e + 2], s3 = col[e + 3];
        float2 v0 = *(const float2*)(y1 + (size_t)s0 * D1 + lane * 2);
        float2 v1 = *(const float2*)(y1 + (size_t)s1 * D1 + lane * 2);
        float2 v2 = *(const float2*)(y1 + (size_t)s2 * D1 + lane * 2);
        float2 v3 = *(const float2*)(y1 + (size_t)s3 * D1 + lane * 2);
        acc.x += (v0.x + v1.x) + (v2.x + v3.x);
        acc.y += (v0.y + v1.y) + (v2.y + v3.y);
    }
    for (; e < r1; ++e) {
        int s0 = col[e];
        float2 v0 = *(const float2*)(y1 + (size_t)s0 * D1 + lane * 2);
        acc.x += v0.x; acc.y += v0.y;
    }
    float di = dinv[wave];
    float2 b = *(const float2*)(b1 + lane * 2);
    float2 h;
    h.x = fmaxf(fmaf(acc.x, di, b.x), 0.f);
    h.y = fmaxf(fmaf(acc.y, di, b.y), 0.f);
    *(float2*)(h1 + (size_t)wave * D1 + lane * 2) = h;
}

// ---------------- layer 2 GEMM: y2 = (h1 @ W2) * dinv ----------------
__global__ __launch_bounds__(256) void k_gemm2(const float* __restrict__ h1,
                                               const float* __restrict__ W2,
                                               const float* __restrict__ dinv,
                                               float* __restrict__ y2) {
    __shared__ float hs[64 * H2STRIDE];  // ~33 KB
    int tid = threadIdx.x;
    int n_base = blockIdx.x * 64;
    {
        int r = tid >> 5;        // 0..7
        int c4 = tid & 31;       // float4 col 0..31
#pragma unroll
        for (int i = 0; i < 8; ++i) {
            int row = r + i * 8;
            int n = n_base + row;
            float4 v{0, 0, 0, 0};
            if (n < NN) v = *(const float4*)(h1 + (size_t)n * D1 + c4 * 4);
            *(float4*)(hs + row * H2STRIDE + c4 * 4) = v;
        }
    }
    __syncthreads();

    int fq = tid & 15;   // f = fq*4, 0..63
    int ng = tid >> 4;   // 0..15, 4 nodes each
    const float* hr = hs + ng * 4 * H2STRIDE;
    const float4* W24 = (const float4*)W2;  // [128][16] float4
    float4 acc0{0, 0, 0, 0}, acc1{0, 0, 0, 0}, acc2{0, 0, 0, 0}, acc3{0, 0, 0, 0};

#pragma unroll 2
    for (int k = 0; k < D1; k += 4) {
        float4 a0 = *(const float4*)(hr + k);
        float4 a1 = *(const float4*)(hr + H2STRIDE + k);
        float4 a2 = *(const float4*)(hr + 2 * H2STRIDE + k);
        float4 a3 = *(const float4*)(hr + 3 * H2STRIDE + k);
        float4 w0 = W24[(k + 0) * 16 + fq];
        float4 w1 = W24[(k + 1) * 16 + fq];
        float4 w2 = W24[(k + 2) * 16 + fq];
        float4 w3 = W24[(k + 3) * 16 + fq];
        fma4(acc0, a0.x, w0); fma4(acc0, a0.y, w1); fma4(acc0, a0.z, w2); fma4(acc0, a0.w, w3);
        fma4(acc1, a1.x, w0); fma4(acc1, a1.y, w1); fma4(acc1, a1.z, w2); fma4(acc1, a1.w, w3);
        fma4(acc2, a2.x, w0); fma4(acc2, a2.y, w1); fma4(acc2, a2.z, w2); fma4(acc2, a2.w, w3);
        fma4(acc3, a3.x, w0); fma4(acc3, a3.y, w1); fma4(acc3, a3.z, w2); fma4(acc3, a3.w, w3);
    }

    int n0 = n_base + ng * 4;
    float4* y24 = (float4*)y2;  // [N][16] float4
    if (n0 + 0 < NN) y24[(size_t)(n0 + 0) * 16 + fq] = scale4(acc0, dinv[n0 + 0]);
    if (n0 + 1 < NN) y24[(size_t)(n0 + 1) * 16 + fq] = scale4(acc1, dinv[n0 + 1]);
    if (n0 + 2 < NN) y24[(size_t)(n0 + 2) * 16 + fq] = scale4(acc2, dinv[n0 + 2]);
    if (n0 + 3 < NN) y24[(size_t)(n0 + 3) * 16 + fq] = scale4(acc3, dinv[n0 + 3]);
}

// ---------------- layer-2 gather fused with FC head ----------------
__global__ __launch_bounds__(256) void k_gather2_final(const int* __restrict__ rowptr,
                                                       const int* __restrict__ col,
                                                       const float* __restrict__ y2,
                                                       const float* __restrict__ dinv,
                                                       const float* __restrict__ b2,
                                                       const float* __restrict__ Wfc,
                                                       const float* __restrict__ bfc,
                                                       float* __restrict__ out) {
    int wave = (blockIdx.x * 256 + threadIdx.x) >> 6;
    int lane = threadIdx.x & 63;
    if (wave >= NN) return;
    int r0 = rowptr[wave], r1 = rowptr[wave + 1];
    float acc = y2[(size_t)wave * D2 + lane];
    int e = r0;
    for (; e + 3 < r1; e += 4) {
        int s0 = col[e], s1 = col[e + 1], s2 = col[e + 2], s3 = col[e + 3];
        float v0 = y2[(size_t)s0 * D2 + lane];
        float v1 = y2[(size_t)s1 * D2 + lane];
        float v2 = y2[(size_t)s2 * D2 + lane];
        float v3 = y2[(size_t)s3 * D2 + lane];
        acc += (v0 + v1) + (v2 + v3);
    }
    for (; e < r1; ++e) acc += y2[(size_t)col[e] * D2 + lane];
    float h = fmaxf(fmaf(acc, dinv[wave], b2[lane]), 0.f);
    float p = h * Wfc[lane];
#pragma unroll
    for (int off = 32; off > 0; off >>= 1)
        p += __shfl_down(p, off, 64);
    if (lane == 0) out[wave] = p + bfc[0];
}

extern "C" void kernel_launch(void* const* d_in, const int* in_sizes, int n_in,
                              void* d_out, int out_size, void* d_ws, size_t ws_size,
                              hipStream_t stream) {
    const float* x   = (const float*)d_in[0];
    const int*   ei  = (const int*)d_in[1];   // [2, E] int
    const float* W1  = (const float*)d_in[2];
    const float* b1  = (const float*)d_in[3];
    const float* W2  = (const float*)d_in[4];
    const float* b2  = (const float*)d_in[5];
    const float* Wfc = (const float*)d_in[6];
    const float* bfc = (const float*)d_in[7];
    float* out = (float*)d_out;

    const int* src = ei;
    const int* dst = ei + NE;

    char* ws = (char*)d_ws;
    size_t o = 0;
    auto alloc = [&](size_t bytes) { char* p = ws + o; o += (bytes + 255) & ~size_t(255); return p; };
    int*   cnt    = (int*)alloc(NN * 4);
    int*   rowptr = (int*)alloc((NN + 1) * 4);
    int*   bsum   = (int*)alloc(512 * 4);
    int*   gcur   = (int*)alloc(NB * 4);
    float* dinv   = (float*)alloc(NN * 4);
    int*   col    = (int*)alloc((size_t)NE * 4);
    float* y1     = (float*)alloc((size_t)NN * D1 * 4);  // y2 aliases y1
    float* h1     = (float*)alloc((size_t)NN * D1 * 4);
    float* y2     = y1;
    unsigned* packed = (unsigned*)h1;  // dead before gemm1 writes... gather1 writes h1

    const int NBn = (NN + 255) / 256;
    const int NBe = (NE + 255) / 256;

    k_zero_cnt   <<<NBn, 256, 0, stream>>>(cnt);
    k_hist       <<<NBe, 256, 0, stream>>>(dst, cnt);
    k_scan_block <<<NBn, 256, 0, stream>>>(cnt, rowptr, bsum);
    k_scan_bsum  <<<1, 512, 0, stream>>>(bsum, gcur);
    k_scan_add   <<<NBn, 256, 0, stream>>>(rowptr, bsum);
    k_dinv       <<<NBn, 256, 0, stream>>>(cnt, dinv);
    k_part       <<<(NE + TILE - 1) / TILE, 256, 0, stream>>>(src, dst, gcur, packed);
    k_fill2      <<<NB, 256, 0, stream>>>(bsum, rowptr, packed, col);

    k_gemm1      <<<NN / 32, 256, 0, stream>>>(x, W1, dinv, y1);
    k_gather1    <<<(NN * 64 + 255) / 256, 256, 0, stream>>>(rowptr, col, y1, dinv, b1, h1);
    k_gemm2      <<<(NN + 63) / 64, 256, 0, stream>>>(h1, W2, dinv, y2);
    k_gather2_final<<<(NN * 64 + 255) / 256, 256, 0, stream>>>(rowptr, col, y2, dinv,
                                                               b2, Wfc, bfc, out);
}

// Round 5
// 393.973 us; speedup vs baseline: 5.5433x; 1.1446x over previous
//
#include <hip/hip_runtime.h>

// ProteinGCN: 2x GCNConv(+relu) + FC head. N=100k, E=1.6M, 64->128->64->1.
// Round 4: (a) layer-1 aggregate-then-transform: gather runs on 64-dim x
// (256 B/edge) instead of 128-dim x@W1 (512 B/edge) -- halves the dominant
// gather's fabric traffic (FETCH 401 MB -> ~200 MB). dinv_s folds into the
// edge fmaf for free. (b) GEMM1+GEMM2 fused into one kernel: h1 lives in LDS
// (64x132 tile), skipping a 102 MB h1 round-trip. 51 KB LDS -> 3 blocks/CU.

constexpr int NN = 100000;
constexpr int NE = 1600000;
constexpr int D0 = 64;   // input dim
constexpr int D1 = 128;  // hidden 1
constexpr int D2 = 64;   // hidden 2
constexpr int NB = (NN + 255) / 256;  // 391 buckets
constexpr int GSTRIDE = 68;           // agg LDS row stride (2-way banks = free)
constexpr int H2STRIDE = 132;         // h1 LDS row stride
constexpr int TILE = 8192;            // edges per k_part block

// ---------------- CSR build ----------------

__global__ __launch_bounds__(256) void k_zero_cnt(int* __restrict__ cnt) {
    int i = blockIdx.x * 256 + threadIdx.x;
    if (i < NN) cnt[i] = 0;
}

__global__ __launch_bounds__(256) void k_hist(const int* __restrict__ dst,
                                              int* __restrict__ cnt) {
    int e = blockIdx.x * 256 + threadIdx.x;
    if (e < NE) atomicAdd(&cnt[dst[e]], 1);
}

__global__ __launch_bounds__(256) void k_scan_block(const int* __restrict__ cnt,
                                                    int* __restrict__ rowptr,
                                                    int* __restrict__ bsum) {
    __shared__ int s[256];
    int tid = threadIdx.x;
    int i = blockIdx.x * 256 + tid;
    int v = (i < NN) ? cnt[i] : 0;
    s[tid] = v;
    __syncthreads();
#pragma unroll
    for (int off = 1; off < 256; off <<= 1) {
        int t = (tid >= off) ? s[tid - off] : 0;
        __syncthreads();
        s[tid] += t;
        __syncthreads();
    }
    if (i < NN) rowptr[i] = s[tid] - v;  // exclusive
    if (tid == 255) bsum[blockIdx.x] = s[255];
}

__global__ __launch_bounds__(512) void k_scan_bsum(int* __restrict__ bsum,
                                                   int* __restrict__ gcur) {
    __shared__ int s[512];
    int tid = threadIdx.x;
    int v = (tid < NB) ? bsum[tid] : 0;
    s[tid] = v;
    __syncthreads();
#pragma unroll
    for (int off = 1; off < 512; off <<= 1) {
        int t = (tid >= off) ? s[tid - off] : 0;
        __syncthreads();
        s[tid] += t;
        __syncthreads();
    }
    int ex = s[tid] - v;  // exclusive scan
    if (tid <= NB) bsum[tid] = ex;   // bsum[NB] == NE
    if (tid < NB) gcur[tid] = ex;
}

__global__ __launch_bounds__(256) void k_scan_add(int* __restrict__ rowptr,
                                                  const int* __restrict__ bsum) {
    int i = blockIdx.x * 256 + threadIdx.x;
    if (i < NN) rowptr[i] += bsum[i >> 8];
    if (i == 0) rowptr[NN] = NE;
}

__global__ __launch_bounds__(256) void k_dinv(const int* __restrict__ cnt,
                                              float* __restrict__ dinv) {
    int i = blockIdx.x * 256 + threadIdx.x;
    if (i < NN) dinv[i] = rsqrtf((float)(cnt[i] + 1));
}

// ---- phase 1: partition edges into dst-buckets, packed (dl<<24)|src ----
__global__ __launch_bounds__(256) void k_part(const int* __restrict__ src,
                                              const int* __restrict__ dst,
                                              int* __restrict__ gcur,
                                              unsigned* __restrict__ packed) {
    __shared__ int cnt_s[NB];
    __shared__ int gbase_s[NB];
    __shared__ int cur_s[NB];
    int tid = threadIdx.x;
    int e0 = blockIdx.x * TILE;
    int ecnt = NE - e0 < TILE ? NE - e0 : TILE;
    for (int i = tid; i < NB; i += 256) cnt_s[i] = 0;
    __syncthreads();
    for (int i = tid; i < ecnt; i += 256)
        atomicAdd(&cnt_s[dst[e0 + i] >> 8], 1);
    __syncthreads();
    for (int i = tid; i < NB; i += 256) {
        int c = cnt_s[i];
        gbase_s[i] = c ? atomicAdd(&gcur[i], c) : 0;
        cur_s[i] = 0;
    }
    __syncthreads();
    for (int i = tid; i < ecnt; i += 256) {
        int d = dst[e0 + i];
        int s = src[e0 + i];
        int b = d >> 8;
        int slot = atomicAdd(&cur_s[b], 1);
        packed[gbase_s[b] + slot] = ((unsigned)(d & 255) << 24) | (unsigned)s;
    }
}

// ---- phase 2: one block per bucket, LDS node cursors, local col writes ----
__global__ __launch_bounds__(256) void k_fill2(const int* __restrict__ bsum,
                                               const int* __restrict__ rowptr,
                                               const unsigned* __restrict__ packed,
                                               int* __restrict__ col) {
    __shared__ int cur[256];
    int b = blockIdx.x;
    int n = (b << 8) + threadIdx.x;
    cur[threadIdx.x] = rowptr[n <= NN ? n : NN];
    __syncthreads();
    int e1 = bsum[b + 1];
    for (int e = bsum[b] + threadIdx.x; e < e1; e += 256) {
        unsigned p = packed[e];
        int pos = atomicAdd(&cur[p >> 24], 1);
        col[pos] = (int)(p & 0xFFFFFFu);
    }
}

// ---------------- helpers ----------------

__device__ __forceinline__ void fma4(float4& acc, float s, const float4& w) {
    acc.x = fmaf(s, w.x, acc.x);
    acc.y = fmaf(s, w.y, acc.y);
    acc.z = fmaf(s, w.z, acc.z);
    acc.w = fmaf(s, w.w, acc.w);
}

__device__ __forceinline__ float4 scale4(const float4& a, float s) {
    return float4{a.x * s, a.y * s, a.z * s, a.w * s};
}

// ---------------- layer-1 gather on raw x (aggregate-then-transform) -------
// agg[d] = dinv_d * ( sum_{s in in(d)} dinv_s * x[s] + dinv_d * x[d] )
__global__ __launch_bounds__(256) void k_gather1x(const int* __restrict__ rowptr,
                                                  const int* __restrict__ col,
                                                  const float* __restrict__ x,
                                                  const float* __restrict__ dinv,
                                                  float* __restrict__ agg) {
    int wave = (blockIdx.x * 256 + threadIdx.x) >> 6;
    int lane = threadIdx.x & 63;
    if (wave >= NN) return;
    int r0 = rowptr[wave], r1 = rowptr[wave + 1];
    float di = dinv[wave];
    float acc = x[(size_t)wave * D0 + lane] * di;
    int e = r0;
    for (; e + 3 < r1; e += 4) {
        int s0 = col[e], s1 = col[e + 1], s2 = col[e + 2], s3 = col[e + 3];
        float d0 = dinv[s0], d1 = dinv[s1], d2 = dinv[s2], d3 = dinv[s3];
        float v0 = x[(size_t)s0 * D0 + lane];
        float v1 = x[(size_t)s1 * D0 + lane];
        float v2 = x[(size_t)s2 * D0 + lane];
        float v3 = x[(size_t)s3 * D0 + lane];
        acc = fmaf(v0, d0, acc);
        acc = fmaf(v1, d1, acc);
        acc = fmaf(v2, d2, acc);
        acc = fmaf(v3, d3, acc);
    }
    for (; e < r1; ++e) {
        int s = col[e];
        acc = fmaf(x[(size_t)s * D0 + lane], dinv[s], acc);
    }
    agg[(size_t)wave * D0 + lane] = acc * di;
}

// ---------------- fused GEMM1 + GEMM2 ----------------
// h1 = relu(agg @ W1 + b1)   (64 -> 128, h1 kept in LDS)
// y2 = (h1 @ W2) * dinv      (128 -> 64)
__global__ __launch_bounds__(256) void k_gemm12(const float* __restrict__ agg,
                                                const float* __restrict__ W1,
                                                const float* __restrict__ b1,
                                                const float* __restrict__ W2,
                                                const float* __restrict__ dinv,
                                                float* __restrict__ y2) {
    __shared__ float as[64 * GSTRIDE];   // 17.4 KB
    __shared__ float hs[64 * H2STRIDE];  // 33.8 KB
    int tid = threadIdx.x;
    int n_base = blockIdx.x * 64;

    // stage 64 agg rows (64 floats each)
    {
        int r = tid >> 4;        // 0..15
        int c4 = tid & 15;       // float4 col 0..15
#pragma unroll
        for (int i = 0; i < 4; ++i) {
            int row = r + i * 16;
            int n = n_base + row;
            float4 v{0, 0, 0, 0};
            if (n < NN) v = *(const float4*)(agg + (size_t)n * D0 + c4 * 4);
            *(float4*)(as + row * GSTRIDE + c4 * 4) = v;
        }
    }
    __syncthreads();

    // phase A: h1 = relu(agg @ W1 + b1); thread = 4 nodes x 8 feats
    {
        int f8 = tid & 15;   // f = f8*8
        int ng = tid >> 4;   // 0..15
        const float* ar = as + ng * 4 * GSTRIDE;
        const float4* W14 = (const float4*)W1;  // [64][32] float4
        float4 a00{0,0,0,0}, a01{0,0,0,0}, a10{0,0,0,0}, a11{0,0,0,0};
        float4 a20{0,0,0,0}, a21{0,0,0,0}, a30{0,0,0,0}, a31{0,0,0,0};
#pragma unroll 4
        for (int k = 0; k < D0; ++k) {
            float s0 = ar[k];
            float s1 = ar[GSTRIDE + k];
            float s2 = ar[2 * GSTRIDE + k];
            float s3 = ar[3 * GSTRIDE + k];
            float4 w0 = W14[k * 32 + f8 * 2];
            float4 w1 = W14[k * 32 + f8 * 2 + 1];
            fma4(a00, s0, w0); fma4(a01, s0, w1);
            fma4(a10, s1, w0); fma4(a11, s1, w1);
            fma4(a20, s2, w0); fma4(a21, s2, w1);
            fma4(a30, s3, w0); fma4(a31, s3, w1);
        }
        float4 bb0 = ((const float4*)b1)[f8 * 2];
        float4 bb1 = ((const float4*)b1)[f8 * 2 + 1];
        float* h0 = hs + (ng * 4) * H2STRIDE + f8 * 8;
        float4 r;
        r.x = fmaxf(a00.x + bb0.x, 0.f); r.y = fmaxf(a00.y + bb0.y, 0.f);
        r.z = fmaxf(a00.z + bb0.z, 0.f); r.w = fmaxf(a00.w + bb0.w, 0.f);
        *(float4*)(h0) = r;
        r.x = fmaxf(a01.x + bb1.x, 0.f); r.y = fmaxf(a01.y + bb1.y, 0.f);
        r.z = fmaxf(a01.z + bb1.z, 0.f); r.w = fmaxf(a01.w + bb1.w, 0.f);
        *(float4*)(h0 + 4) = r;
        r.x = fmaxf(a10.x + bb0.x, 0.f); r.y = fmaxf(a10.y + bb0.y, 0.f);
        r.z = fmaxf(a10.z + bb0.z, 0.f); r.w = fmaxf(a10.w + bb0.w, 0.f);
        *(float4*)(h0 + H2STRIDE) = r;
        r.x = fmaxf(a11.x + bb1.x, 0.f); r.y = fmaxf(a11.y + bb1.y, 0.f);
        r.z = fmaxf(a11.z + bb1.z, 0.f); r.w = fmaxf(a11.w + bb1.w, 0.f);
        *(float4*)(h0 + H2STRIDE + 4) = r;
        r.x = fmaxf(a20.x + bb0.x, 0.f); r.y = fmaxf(a20.y + bb0.y, 0.f);
        r.z = fmaxf(a20.z + bb0.z, 0.f); r.w = fmaxf(a20.w + bb0.w, 0.f);
        *(float4*)(h0 + 2 * H2STRIDE) = r;
        r.x = fmaxf(a21.x + bb1.x, 0.f); r.y = fmaxf(a21.y + bb1.y, 0.f);
        r.z = fmaxf(a21.z + bb1.z, 0.f); r.w = fmaxf(a21.w + bb1.w, 0.f);
        *(float4*)(h0 + 2 * H2STRIDE + 4) = r;
        r.x = fmaxf(a30.x + bb0.x, 0.f); r.y = fmaxf(a30.y + bb0.y, 0.f);
        r.z = fmaxf(a30.z + bb0.z, 0.f); r.w = fmaxf(a30.w + bb0.w, 0.f);
        *(float4*)(h0 + 3 * H2STRIDE) = r;
        r.x = fmaxf(a31.x + bb1.x, 0.f); r.y = fmaxf(a31.y + bb1.y, 0.f);
        r.z = fmaxf(a31.z + bb1.z, 0.f); r.w = fmaxf(a31.w + bb1.w, 0.f);
        *(float4*)(h0 + 3 * H2STRIDE + 4) = r;
    }
    __syncthreads();

    // phase B: y2 = (h1 @ W2) * dinv; thread = 4 nodes x 4 feats, K=128
    {
        int fq = tid & 15;   // f = fq*4
        int ng = tid >> 4;   // 0..15
        const float* hr = hs + ng * 4 * H2STRIDE;
        const float4* W24 = (const float4*)W2;  // [128][16] float4
        float4 acc0{0,0,0,0}, acc1{0,0,0,0}, acc2{0,0,0,0}, acc3{0,0,0,0};
#pragma unroll 2
        for (int k = 0; k < D1; k += 4) {
            float4 a0 = *(const float4*)(hr + k);
            float4 a1 = *(const float4*)(hr + H2STRIDE + k);
            float4 a2 = *(const float4*)(hr + 2 * H2STRIDE + k);
            float4 a3 = *(const float4*)(hr + 3 * H2STRIDE + k);
            float4 w0 = W24[(k + 0) * 16 + fq];
            float4 w1 = W24[(k + 1) * 16 + fq];
            float4 w2 = W24[(k + 2) * 16 + fq];
            float4 w3 = W24[(k + 3) * 16 + fq];
            fma4(acc0, a0.x, w0); fma4(acc0, a0.y, w1); fma4(acc0, a0.z, w2); fma4(acc0, a0.w, w3);
            fma4(acc1, a1.x, w0); fma4(acc1, a1.y, w1); fma4(acc1, a1.z, w2); fma4(acc1, a1.w, w3);
            fma4(acc2, a2.x, w0); fma4(acc2, a2.y, w1); fma4(acc2, a2.z, w2); fma4(acc2, a2.w, w3);
            fma4(acc3, a3.x, w0); fma4(acc3, a3.y, w1); fma4(acc3, a3.z, w2); fma4(acc3, a3.w, w3);
        }
        int n0 = n_base + ng * 4;
        float4* y24 = (float4*)y2;  // [N][16] float4
        if (n0 + 0 < NN) y24[(size_t)(n0 + 0) * 16 + fq] = scale4(acc0, dinv[n0 + 0]);
        if (n0 + 1 < NN) y24[(size_t)(n0 + 1) * 16 + fq] = scale4(acc1, dinv[n0 + 1]);
        if (n0 + 2 < NN) y24[(size_t)(n0 + 2) * 16 + fq] = scale4(acc2, dinv[n0 + 2]);
        if (n0 + 3 < NN) y24[(size_t)(n0 + 3) * 16 + fq] = scale4(acc3, dinv[n0 + 3]);
    }
}

// ---------------- layer-2 gather fused with FC head ----------------
__global__ __launch_bounds__(256) void k_gather2_final(const int* __restrict__ rowptr,
                                                       const int* __restrict__ col,
                                                       const float* __restrict__ y2,
                                                       const float* __restrict__ dinv,
                                                       const float* __restrict__ b2,
                                                       const float* __restrict__ Wfc,
                                                       const float* __restrict__ bfc,
                                                       float* __restrict__ out) {
    int wave = (blockIdx.x * 256 + threadIdx.x) >> 6;
    int lane = threadIdx.x & 63;
    if (wave >= NN) return;
    int r0 = rowptr[wave], r1 = rowptr[wave + 1];
    float acc = y2[(size_t)wave * D2 + lane];
    int e = r0;
    for (; e + 3 < r1; e += 4) {
        int s0 = col[e], s1 = col[e + 1], s2 = col[e + 2], s3 = col[e + 3];
        float v0 = y2[(size_t)s0 * D2 + lane];
        float v1 = y2[(size_t)s1 * D2 + lane];
        float v2 = y2[(size_t)s2 * D2 + lane];
        float v3 = y2[(size_t)s3 * D2 + lane];
        acc += (v0 + v1) + (v2 + v3);
    }
    for (; e < r1; ++e) acc += y2[(size_t)col[e] * D2 + lane];
    float h = fmaxf(fmaf(acc, dinv[wave], b2[lane]), 0.f);
    float p = h * Wfc[lane];
#pragma unroll
    for (int off = 32; off > 0; off >>= 1)
        p += __shfl_down(p, off, 64);
    if (lane == 0) out[wave] = p + bfc[0];
}

extern "C" void kernel_launch(void* const* d_in, const int* in_sizes, int n_in,
                              void* d_out, int out_size, void* d_ws, size_t ws_size,
                              hipStream_t stream) {
    const float* x   = (const float*)d_in[0];
    const int*   ei  = (const int*)d_in[1];   // [2, E] int
    const float* W1  = (const float*)d_in[2];
    const float* b1  = (const float*)d_in[3];
    const float* W2  = (const float*)d_in[4];
    const float* b2  = (const float*)d_in[5];
    const float* Wfc = (const float*)d_in[6];
    const float* bfc = (const float*)d_in[7];
    float* out = (float*)d_out;

    const int* src = ei;
    const int* dst = ei + NE;

    char* ws = (char*)d_ws;
    size_t o = 0;
    auto alloc = [&](size_t bytes) { char* p = ws + o; o += (bytes + 255) & ~size_t(255); return p; };
    int*   cnt    = (int*)alloc(NN * 4);
    int*   rowptr = (int*)alloc((NN + 1) * 4);
    int*   bsum   = (int*)alloc(512 * 4);
    int*   gcur   = (int*)alloc(NB * 4);
    float* dinv   = (float*)alloc(NN * 4);
    int*   col    = (int*)alloc((size_t)NE * 4);
    float* agg1x  = (float*)alloc((size_t)NN * D0 * 4);  // 25.6 MB
    float* y2     = (float*)alloc((size_t)NN * D2 * 4);  // 25.6 MB
    unsigned* packed = (unsigned*)agg1x;  // dead before k_gather1x writes agg

    const int NBn = (NN + 255) / 256;
    const int NBe = (NE + 255) / 256;

    k_zero_cnt   <<<NBn, 256, 0, stream>>>(cnt);
    k_hist       <<<NBe, 256, 0, stream>>>(dst, cnt);
    k_scan_block <<<NBn, 256, 0, stream>>>(cnt, rowptr, bsum);
    k_scan_bsum  <<<1, 512, 0, stream>>>(bsum, gcur);
    k_scan_add   <<<NBn, 256, 0, stream>>>(rowptr, bsum);
    k_dinv       <<<NBn, 256, 0, stream>>>(cnt, dinv);
    k_part       <<<(NE + TILE - 1) / TILE, 256, 0, stream>>>(src, dst, gcur, packed);
    k_fill2      <<<NB, 256, 0, stream>>>(bsum, rowptr, packed, col);

    k_gather1x   <<<(NN * 64 + 255) / 256, 256, 0, stream>>>(rowptr, col, x, dinv, agg1x);
    k_gemm12     <<<(NN + 63) / 64, 256, 0, stream>>>(agg1x, W1, b1, W2, dinv, y2);
    k_gather2_final<<<(NN * 64 + 255) / 256, 256, 0, stream>>>(rowptr, col, y2, dinv,
                                                               b2, Wfc, bfc, out);
}

// Round 6
// 381.239 us; speedup vs baseline: 5.7285x; 1.0334x over previous
//
#include <hip/hip_runtime.h>

// ProteinGCN: 2x GCNConv(+relu) + FC head. N=100k, E=1.6M, 64->128->64->1.
// Round 5: gathers were latency/issue-bound (36% HBM, 30% VALU, nothing
// saturated; fetch volume already ~92% of the random-graph scheduling floor).
// Rework both gathers to a float4-per-lane layout: lane=(f4=lane&15,
// es=lane>>4), one VMEM instr covers 4 edges (64 lanes x 16 B), unrolled x2
// (8 edges / 2 KB in flight per wave-iter), es-partials merged with 2
// shfl_xor. Prescale xs = x*dinv once (streaming) so the edge op is a plain
// add (no per-edge dinv load). FC head reduced via xor-shuffles.

constexpr int NN = 100000;
constexpr int NE = 1600000;
constexpr int D0 = 64;   // input dim
constexpr int D1 = 128;  // hidden 1
constexpr int D2 = 64;   // hidden 2
constexpr int NB = (NN + 255) / 256;  // 391 buckets
constexpr int GSTRIDE = 68;           // agg LDS row stride
constexpr int H2STRIDE = 132;         // h1 LDS row stride
constexpr int TILE = 8192;            // edges per k_part block

// ---------------- CSR build ----------------

__global__ __launch_bounds__(256) void k_zero_cnt(int* __restrict__ cnt) {
    int i = blockIdx.x * 256 + threadIdx.x;
    if (i < NN) cnt[i] = 0;
}

__global__ __launch_bounds__(256) void k_hist(const int* __restrict__ dst,
                                              int* __restrict__ cnt) {
    int e = blockIdx.x * 256 + threadIdx.x;
    if (e < NE) atomicAdd(&cnt[dst[e]], 1);
}

__global__ __launch_bounds__(256) void k_scan_block(const int* __restrict__ cnt,
                                                    int* __restrict__ rowptr,
                                                    int* __restrict__ bsum) {
    __shared__ int s[256];
    int tid = threadIdx.x;
    int i = blockIdx.x * 256 + tid;
    int v = (i < NN) ? cnt[i] : 0;
    s[tid] = v;
    __syncthreads();
#pragma unroll
    for (int off = 1; off < 256; off <<= 1) {
        int t = (tid >= off) ? s[tid - off] : 0;
        __syncthreads();
        s[tid] += t;
        __syncthreads();
    }
    if (i < NN) rowptr[i] = s[tid] - v;  // exclusive
    if (tid == 255) bsum[blockIdx.x] = s[255];
}

__global__ __launch_bounds__(512) void k_scan_bsum(int* __restrict__ bsum,
                                                   int* __restrict__ gcur) {
    __shared__ int s[512];
    int tid = threadIdx.x;
    int v = (tid < NB) ? bsum[tid] : 0;
    s[tid] = v;
    __syncthreads();
#pragma unroll
    for (int off = 1; off < 512; off <<= 1) {
        int t = (tid >= off) ? s[tid - off] : 0;
        __syncthreads();
        s[tid] += t;
        __syncthreads();
    }
    int ex = s[tid] - v;  // exclusive scan
    if (tid <= NB) bsum[tid] = ex;   // bsum[NB] == NE
    if (tid < NB) gcur[tid] = ex;
}

__global__ __launch_bounds__(256) void k_scan_add(int* __restrict__ rowptr,
                                                  const int* __restrict__ bsum) {
    int i = blockIdx.x * 256 + threadIdx.x;
    if (i < NN) rowptr[i] += bsum[i >> 8];
    if (i == 0) rowptr[NN] = NE;
}

__global__ __launch_bounds__(256) void k_dinv(const int* __restrict__ cnt,
                                              float* __restrict__ dinv) {
    int i = blockIdx.x * 256 + threadIdx.x;
    if (i < NN) dinv[i] = rsqrtf((float)(cnt[i] + 1));
}

// ---- phase 1: partition edges into dst-buckets, packed (dl<<24)|src ----
__global__ __launch_bounds__(256) void k_part(const int* __restrict__ src,
                                              const int* __restrict__ dst,
                                              int* __restrict__ gcur,
                                              unsigned* __restrict__ packed) {
    __shared__ int cnt_s[NB];
    __shared__ int gbase_s[NB];
    __shared__ int cur_s[NB];
    int tid = threadIdx.x;
    int e0 = blockIdx.x * TILE;
    int ecnt = NE - e0 < TILE ? NE - e0 : TILE;
    for (int i = tid; i < NB; i += 256) cnt_s[i] = 0;
    __syncthreads();
    for (int i = tid; i < ecnt; i += 256)
        atomicAdd(&cnt_s[dst[e0 + i] >> 8], 1);
    __syncthreads();
    for (int i = tid; i < NB; i += 256) {
        int c = cnt_s[i];
        gbase_s[i] = c ? atomicAdd(&gcur[i], c) : 0;
        cur_s[i] = 0;
    }
    __syncthreads();
    for (int i = tid; i < ecnt; i += 256) {
        int d = dst[e0 + i];
        int s = src[e0 + i];
        int b = d >> 8;
        int slot = atomicAdd(&cur_s[b], 1);
        packed[gbase_s[b] + slot] = ((unsigned)(d & 255) << 24) | (unsigned)s;
    }
}

// ---- phase 2: one block per bucket, LDS node cursors, local col writes ----
__global__ __launch_bounds__(256) void k_fill2(const int* __restrict__ bsum,
                                               const int* __restrict__ rowptr,
                                               const unsigned* __restrict__ packed,
                                               int* __restrict__ col) {
    __shared__ int cur[256];
    int b = blockIdx.x;
    int n = (b << 8) + threadIdx.x;
    cur[threadIdx.x] = rowptr[n <= NN ? n : NN];
    __syncthreads();
    int e1 = bsum[b + 1];
    for (int e = bsum[b] + threadIdx.x; e < e1; e += 256) {
        unsigned p = packed[e];
        int pos = atomicAdd(&cur[p >> 24], 1);
        col[pos] = (int)(p & 0xFFFFFFu);
    }
}

// ---------------- helpers ----------------

__device__ __forceinline__ void fma4(float4& acc, float s, const float4& w) {
    acc.x = fmaf(s, w.x, acc.x);
    acc.y = fmaf(s, w.y, acc.y);
    acc.z = fmaf(s, w.z, acc.z);
    acc.w = fmaf(s, w.w, acc.w);
}

__device__ __forceinline__ float4 scale4(const float4& a, float s) {
    return float4{a.x * s, a.y * s, a.z * s, a.w * s};
}

__device__ __forceinline__ void add4(float4& a, const float4& b) {
    a.x += b.x; a.y += b.y; a.z += b.z; a.w += b.w;
}

__device__ __forceinline__ void xor_reduce4(float4& a, int mask) {
    a.x += __shfl_xor(a.x, mask, 64);
    a.y += __shfl_xor(a.y, mask, 64);
    a.z += __shfl_xor(a.z, mask, 64);
    a.w += __shfl_xor(a.w, mask, 64);
}

// ---------------- prescale: xs = x * dinv ----------------
__global__ __launch_bounds__(256) void k_prescale(const float* __restrict__ x,
                                                  const float* __restrict__ dinv,
                                                  float* __restrict__ xs) {
    int i = blockIdx.x * 256 + threadIdx.x;  // float4 index
    if (i >= NN * 16) return;
    float di = dinv[i >> 4];
    ((float4*)xs)[i] = scale4(((const float4*)x)[i], di);
}

// ---------------- layer-1 gather on prescaled xs ----------------
// agg[d] = dinv_d * ( xs[d] + sum_{s in in(d)} xs[s] )
__global__ __launch_bounds__(256) void k_gather1x(const int* __restrict__ rowptr,
                                                  const int* __restrict__ col,
                                                  const float* __restrict__ xs,
                                                  const float* __restrict__ dinv,
                                                  float* __restrict__ agg) {
    int wave = (blockIdx.x * 256 + threadIdx.x) >> 6;
    int lane = threadIdx.x & 63;
    if (wave >= NN) return;
    int f4 = lane & 15;   // float4 index within 64-float row
    int es = lane >> 4;   // edge sublane 0..3
    int r0 = rowptr[wave], r1 = rowptr[wave + 1];
    const float4* xs4 = (const float4*)xs;
    float4 acc{0, 0, 0, 0};
    if (es == 0) acc = xs4[(size_t)wave * 16 + f4];  // self loop (once)
    int e = r0 + es;
    for (; e + 4 < r1; e += 8) {
        int s0 = col[e];
        int s1 = col[e + 4];
        float4 v0 = xs4[(size_t)s0 * 16 + f4];
        float4 v1 = xs4[(size_t)s1 * 16 + f4];
        add4(acc, v0);
        add4(acc, v1);
    }
    for (; e < r1; e += 4) {
        float4 v = xs4[(size_t)col[e] * 16 + f4];
        add4(acc, v);
    }
    xor_reduce4(acc, 16);
    xor_reduce4(acc, 32);
    if (es == 0)
        ((float4*)agg)[(size_t)wave * 16 + f4] = scale4(acc, dinv[wave]);
}

// ---------------- fused GEMM1 + GEMM2 ----------------
// h1 = relu(agg @ W1 + b1)   (64 -> 128, h1 kept in LDS)
// y2 = (h1 @ W2) * dinv      (128 -> 64)
__global__ __launch_bounds__(256) void k_gemm12(const float* __restrict__ agg,
                                                const float* __restrict__ W1,
                                                const float* __restrict__ b1,
                                                const float* __restrict__ W2,
                                                const float* __restrict__ dinv,
                                                float* __restrict__ y2) {
    __shared__ float as[64 * GSTRIDE];   // 17.4 KB
    __shared__ float hs[64 * H2STRIDE];  // 33.8 KB
    int tid = threadIdx.x;
    int n_base = blockIdx.x * 64;

    // stage 64 agg rows (64 floats each)
    {
        int r = tid >> 4;        // 0..15
        int c4 = tid & 15;       // float4 col 0..15
#pragma unroll
        for (int i = 0; i < 4; ++i) {
            int row = r + i * 16;
            int n = n_base + row;
            float4 v{0, 0, 0, 0};
            if (n < NN) v = *(const float4*)(agg + (size_t)n * D0 + c4 * 4);
            *(float4*)(as + row * GSTRIDE + c4 * 4) = v;
        }
    }
    __syncthreads();

    // phase A: h1 = relu(agg @ W1 + b1); thread = 4 nodes x 8 feats
    {
        int f8 = tid & 15;   // f = f8*8
        int ng = tid >> 4;   // 0..15
        const float* ar = as + ng * 4 * GSTRIDE;
        const float4* W14 = (const float4*)W1;  // [64][32] float4
        float4 a00{0,0,0,0}, a01{0,0,0,0}, a10{0,0,0,0}, a11{0,0,0,0};
        float4 a20{0,0,0,0}, a21{0,0,0,0}, a30{0,0,0,0}, a31{0,0,0,0};
#pragma unroll 4
        for (int k = 0; k < D0; ++k) {
            float s0 = ar[k];
            float s1 = ar[GSTRIDE + k];
            float s2 = ar[2 * GSTRIDE + k];
            float s3 = ar[3 * GSTRIDE + k];
            float4 w0 = W14[k * 32 + f8 * 2];
            float4 w1 = W14[k * 32 + f8 * 2 + 1];
            fma4(a00, s0, w0); fma4(a01, s0, w1);
            fma4(a10, s1, w0); fma4(a11, s1, w1);
            fma4(a20, s2, w0); fma4(a21, s2, w1);
            fma4(a30, s3, w0); fma4(a31, s3, w1);
        }
        float4 bb0 = ((const float4*)b1)[f8 * 2];
        float4 bb1 = ((const float4*)b1)[f8 * 2 + 1];
        float* h0 = hs + (ng * 4) * H2STRIDE + f8 * 8;
        float4 r;
        r.x = fmaxf(a00.x + bb0.x, 0.f); r.y = fmaxf(a00.y + bb0.y, 0.f);
        r.z = fmaxf(a00.z + bb0.z, 0.f); r.w = fmaxf(a00.w + bb0.w, 0.f);
        *(float4*)(h0) = r;
        r.x = fmaxf(a01.x + bb1.x, 0.f); r.y = fmaxf(a01.y + bb1.y, 0.f);
        r.z = fmaxf(a01.z + bb1.z, 0.f); r.w = fmaxf(a01.w + bb1.w, 0.f);
        *(float4*)(h0 + 4) = r;
        r.x = fmaxf(a10.x + bb0.x, 0.f); r.y = fmaxf(a10.y + bb0.y, 0.f);
        r.z = fmaxf(a10.z + bb0.z, 0.f); r.w = fmaxf(a10.w + bb0.w, 0.f);
        *(float4*)(h0 + H2STRIDE) = r;
        r.x = fmaxf(a11.x + bb1.x, 0.f); r.y = fmaxf(a11.y + bb1.y, 0.f);
        r.z = fmaxf(a11.z + bb1.z, 0.f); r.w = fmaxf(a11.w + bb1.w, 0.f);
        *(float4*)(h0 + H2STRIDE + 4) = r;
        r.x = fmaxf(a20.x + bb0.x, 0.f); r.y = fmaxf(a20.y + bb0.y, 0.f);
        r.z = fmaxf(a20.z + bb0.z, 0.f); r.w = fmaxf(a20.w + bb0.w, 0.f);
        *(float4*)(h0 + 2 * H2STRIDE) = r;
        r.x = fmaxf(a21.x + bb1.x, 0.f); r.y = fmaxf(a21.y + bb1.y, 0.f);
        r.z = fmaxf(a21.z + bb1.z, 0.f); r.w = fmaxf(a21.w + bb1.w, 0.f);
        *(float4*)(h0 + 2 * H2STRIDE + 4) = r;
        r.x = fmaxf(a30.x + bb0.x, 0.f); r.y = fmaxf(a30.y + bb0.y, 0.f);
        r.z = fmaxf(a30.z + bb0.z, 0.f); r.w = fmaxf(a30.w + bb0.w, 0.f);
        *(float4*)(h0 + 3 * H2STRIDE) = r;
        r.x = fmaxf(a31.x + bb1.x, 0.f); r.y = fmaxf(a31.y + bb1.y, 0.f);
        r.z = fmaxf(a31.z + bb1.z, 0.f); r.w = fmaxf(a31.w + bb1.w, 0.f);
        *(float4*)(h0 + 3 * H2STRIDE + 4) = r;
    }
    __syncthreads();

    // phase B: y2 = (h1 @ W2) * dinv; thread = 4 nodes x 4 feats, K=128
    {
        int fq = tid & 15;   // f = fq*4
        int ng = tid >> 4;   // 0..15
        const float* hr = hs + ng * 4 * H2STRIDE;
        const float4* W24 = (const float4*)W2;  // [128][16] float4
        float4 acc0{0,0,0,0}, acc1{0,0,0,0}, acc2{0,0,0,0}, acc3{0,0,0,0};
#pragma unroll 2
        for (int k = 0; k < D1; k += 4) {
            float4 a0 = *(const float4*)(hr + k);
            float4 a1 = *(const float4*)(hr + H2STRIDE + k);
            float4 a2 = *(const float4*)(hr + 2 * H2STRIDE + k);
            float4 a3 = *(const float4*)(hr + 3 * H2STRIDE + k);
            float4 w0 = W24[(k + 0) * 16 + fq];
            float4 w1 = W24[(k + 1) * 16 + fq];
            float4 w2 = W24[(k + 2) * 16 + fq];
            float4 w3 = W24[(k + 3) * 16 + fq];
            fma4(acc0, a0.x, w0); fma4(acc0, a0.y, w1); fma4(acc0, a0.z, w2); fma4(acc0, a0.w, w3);
            fma4(acc1, a1.x, w0); fma4(acc1, a1.y, w1); fma4(acc1, a1.z, w2); fma4(acc1, a1.w, w3);
            fma4(acc2, a2.x, w0); fma4(acc2, a2.y, w1); fma4(acc2, a2.z, w2); fma4(acc2, a2.w, w3);
            fma4(acc3, a3.x, w0); fma4(acc3, a3.y, w1); fma4(acc3, a3.z, w2); fma4(acc3, a3.w, w3);
        }
        int n0 = n_base + ng * 4;
        float4* y24 = (float4*)y2;  // [N][16] float4
        if (n0 + 0 < NN) y24[(size_t)(n0 + 0) * 16 + fq] = scale4(acc0, dinv[n0 + 0]);
        if (n0 + 1 < NN) y24[(size_t)(n0 + 1) * 16 + fq] = scale4(acc1, dinv[n0 + 1]);
        if (n0 + 2 < NN) y24[(size_t)(n0 + 2) * 16 + fq] = scale4(acc2, dinv[n0 + 2]);
        if (n0 + 3 < NN) y24[(size_t)(n0 + 3) * 16 + fq] = scale4(acc3, dinv[n0 + 3]);
    }
}

// ---------------- layer-2 gather fused with FC head ----------------
// acc = y2[d] + sum y2[s]; out[d] = relu(acc*dinv_d + b2) . Wfc + bfc
__global__ __launch_bounds__(256) void k_gather2_final(const int* __restrict__ rowptr,
                                                       const int* __restrict__ col,
                                                       const float* __restrict__ y2,
                                                       const float* __restrict__ dinv,
                                                       const float* __restrict__ b2,
                                                       const float* __restrict__ Wfc,
                                                       const float* __restrict__ bfc,
                                                       float* __restrict__ out) {
    int wave = (blockIdx.x * 256 + threadIdx.x) >> 6;
    int lane = threadIdx.x & 63;
    if (wave >= NN) return;
    int f4 = lane & 15;
    int es = lane >> 4;
    int r0 = rowptr[wave], r1 = rowptr[wave + 1];
    const float4* y24 = (const float4*)y2;
    float4 acc{0, 0, 0, 0};
    if (es == 0) acc = y24[(size_t)wave * 16 + f4];  // self loop (once)
    int e = r0 + es;
    for (; e + 4 < r1; e += 8) {
        int s0 = col[e];
        int s1 = col[e + 4];
        float4 v0 = y24[(size_t)s0 * 16 + f4];
        float4 v1 = y24[(size_t)s1 * 16 + f4];
        add4(acc, v0);
        add4(acc, v1);
    }
    for (; e < r1; e += 4) {
        float4 v = y24[(size_t)col[e] * 16 + f4];
        add4(acc, v);
    }
    xor_reduce4(acc, 16);
    xor_reduce4(acc, 32);
    // every lane now holds the feature-group sum for its f4 (4 copies)
    float di = dinv[wave];
    float4 b = ((const float4*)b2)[f4];
    float4 w = ((const float4*)Wfc)[f4];
    float p = fmaxf(fmaf(acc.x, di, b.x), 0.f) * w.x
            + fmaxf(fmaf(acc.y, di, b.y), 0.f) * w.y
            + fmaxf(fmaf(acc.z, di, b.z), 0.f) * w.z
            + fmaxf(fmaf(acc.w, di, b.w), 0.f) * w.w;
    // sum the 16 f4 groups (each 16-lane block holds all 16 f4 values)
    p += __shfl_xor(p, 1, 64);
    p += __shfl_xor(p, 2, 64);
    p += __shfl_xor(p, 4, 64);
    p += __shfl_xor(p, 8, 64);
    if (lane == 0) out[wave] = p + bfc[0];
}

extern "C" void kernel_launch(void* const* d_in, const int* in_sizes, int n_in,
                              void* d_out, int out_size, void* d_ws, size_t ws_size,
                              hipStream_t stream) {
    const float* x   = (const float*)d_in[0];
    const int*   ei  = (const int*)d_in[1];   // [2, E] int
    const float* W1  = (const float*)d_in[2];
    const float* b1  = (const float*)d_in[3];
    const float* W2  = (const float*)d_in[4];
    const float* b2  = (const float*)d_in[5];
    const float* Wfc = (const float*)d_in[6];
    const float* bfc = (const float*)d_in[7];
    float* out = (float*)d_out;

    const int* src = ei;
    const int* dst = ei + NE;

    char* ws = (char*)d_ws;
    size_t o = 0;
    auto alloc = [&](size_t bytes) { char* p = ws + o; o += (bytes + 255) & ~size_t(255); return p; };
    int*   cnt    = (int*)alloc(NN * 4);
    int*   rowptr = (int*)alloc((NN + 1) * 4);
    int*   bsum   = (int*)alloc(512 * 4);
    int*   gcur   = (int*)alloc(NB * 4);
    float* dinv   = (float*)alloc(NN * 4);
    int*   col    = (int*)alloc((size_t)NE * 4);
    float* xs     = (float*)alloc((size_t)NN * D0 * 4);  // 25.6 MB
    float* agg1x  = (float*)alloc((size_t)NN * D0 * 4);  // 25.6 MB
    float* y2     = (float*)alloc((size_t)NN * D2 * 4);  // 25.6 MB
    unsigned* packed = (unsigned*)agg1x;  // dead before k_gather1x writes agg

    const int NBn = (NN + 255) / 256;
    const int NBe = (NE + 255) / 256;

    k_zero_cnt   <<<NBn, 256, 0, stream>>>(cnt);
    k_hist       <<<NBe, 256, 0, stream>>>(dst, cnt);
    k_scan_block <<<NBn, 256, 0, stream>>>(cnt, rowptr, bsum);
    k_scan_bsum  <<<1, 512, 0, stream>>>(bsum, gcur);
    k_scan_add   <<<NBn, 256, 0, stream>>>(rowptr, bsum);
    k_dinv       <<<NBn, 256, 0, stream>>>(cnt, dinv);
    k_part       <<<(NE + TILE - 1) / TILE, 256, 0, stream>>>(src, dst, gcur, packed);
    k_fill2      <<<NB, 256, 0, stream>>>(bsum, rowptr, packed, col);
    k_prescale   <<<(NN * 16 + 255) / 256, 256, 0, stream>>>(x, dinv, xs);

    k_gather1x   <<<(NN * 64 + 255) / 256, 256, 0, stream>>>(rowptr, col, xs, dinv, agg1x);
    k_gemm12     <<<(NN + 63) / 64, 256, 0, stream>>>(agg1x, W1, b1, W2, dinv, y2);
    k_gather2_final<<<(NN * 64 + 255) / 256, 256, 0, stream>>>(rowptr, col, y2, dinv,
                                                               b2, Wfc, bfc, out);
}